// Round 1
// baseline (428.346 us; speedup 1.0000x reference)
//
#include <hip/hip_runtime.h>
#include <hip/hip_bf16.h>

// Problem constants (B=4, S=2048, D=2048, F=8192, G=8, K=1)
#define T_TOK 8192   // B*S tokens
#define D_DIM 2048
#define F_DIM 8192
#define G_NUM 8
#define GF    1024   // features per group = F/G
#define GATE_Q 16    // gate d-chunks (was 4) -> 2048 one-wave blocks, ~8 waves/CU
#define GATE_D 128   // D_DIM / GATE_Q

typedef __attribute__((ext_vector_type(8))) short bf16x8;  // 8 bf16 (4 VGPRs)
typedef __attribute__((ext_vector_type(4))) float f32x4;

// async global->LDS, 16B per lane. HW semantics: LDS dest = wave-uniform base
// (first lane's value) + lane*16; global address is per-lane (gather is fine).
__device__ __forceinline__ void async_load16(const void* g, void* l) {
    __builtin_amdgcn_global_load_lds(
        (const __attribute__((address_space(1))) unsigned int*)g,
        (__attribute__((address_space(3))) unsigned int*)l, 16, 0, 0);
}

__device__ __forceinline__ unsigned short f2bf(float f) {
    unsigned int u = __float_as_uint(f);
    unsigned int r = (u + 0x7fffu + ((u >> 16) & 1u)) >> 16;  // RNE
    return (unsigned short)r;
}

__device__ __forceinline__ uint2 pack4(float4 v) {
    union { __hip_bfloat162 b; unsigned u; } c0, c1;
    c0.b = __float22bfloat162_rn({v.x, v.y});
    c1.b = __float22bfloat162_rn({v.z, v.w});
    uint2 r; r.x = c0.u; r.y = c1.u; return r;
}

// ---------------------------------------------------------------------------
// ws layout:
//   [0,32B) cnt | [1KiB,257KiB) bucket[8][8192]
//   part (fp64, 8 MiB: 8192 tok x 16 q x 8 g) @ 0.5 MiB -- ALIASES Hb;
//     consumed by combine before gemm1 writes Hb (stream-ordered, safe)
//   Hb  @ 0.5  (16 MiB bf16 H)
//   xb  @ 16.5 (32 MiB bf16 x)          [FAST+MID]
//   W1b @ 48.5 (32 MiB), W2b @ 80.5 (32 MiB)   [FAST only]
// FAST needs 112.5 MiB; MID needs 48.5 MiB; SAFE needs 16.5 MiB.
// ---------------------------------------------------------------------------

__global__ void zero_cnt_kernel(int* __restrict__ cnt) {
    if (threadIdx.x < G_NUM) cnt[threadIdx.x] = 0;
}

// fp32 -> bf16, 8 elems/thread
__global__ __launch_bounds__(256)
void convert_kernel(const float* __restrict__ src, unsigned short* __restrict__ dst, int n) {
    int i = (blockIdx.x * 256 + threadIdx.x) * 8;
    if (i >= n) return;
    float4 a = *(const float4*)(src + i);
    float4 b = *(const float4*)(src + i + 4);
    uint2 p0 = pack4(a), p1 = pack4(b);
    uint4 o; o.x = p0.x; o.y = p0.y; o.z = p1.x; o.w = p1.y;
    *(uint4*)(dst + i) = o;
}

// ---------------------------------------------------------------------------
// Gate phase 1: lane = token. Block = 1 wave (64 thr). Grid = (16 d-chunks,
// 128 token-tiles) = 2048 blocks (~8 waves/CU; was 512 blocks = 2 waves/CU,
// latency-bound). Each block: stage Wm chunk [8][128]; stream x in two 64-d
// sub-chunks through LDS with register prefetch; 8 fp64 accs per lane.
// Fused fp32->bf16 conversion of x written to xb (WRITE_XB).
// ---------------------------------------------------------------------------
template <bool WRITE_XB>
__global__ __launch_bounds__(64)
void gate_partial_kernel(const float* __restrict__ x, const float* __restrict__ Wm,
                         unsigned short* __restrict__ xb, double* __restrict__ part) {
    const int q     = blockIdx.x;      // d-chunk
    const int t     = blockIdx.y;      // token tile
    const int lane  = threadIdx.x;
    const int tok0  = t * 64;
    const int kbase = q * GATE_D;

    __shared__ float wmS[8][GATE_D];   // 4 KiB, wave-uniform reads (broadcast)
    __shared__ float xs[64][68];       // 17.4 KiB; stride 68 floats = 17*16B

    // preload Wm chunk: 1024 floats, 4 float4 per lane
    for (int i = lane * 4; i < 8 * GATE_D; i += 64 * 4) {
        int g = i >> 7, d = i & (GATE_D - 1);
        *(float4*)&wmS[g][d] = *(const float4*)(Wm + (size_t)g * D_DIM + kbase + d);
    }

    double acc[8] = {0, 0, 0, 0, 0, 0, 0, 0};

    const int srow = lane >> 2;        // 0..15
    const int scol = (lane & 3) * 4;   // 0,4,8,12 (floats)

    float4 v[16];
    // chunk = 64 tokens x 64 d. 16 float4/lane: row = it*16+srow, col = ci*16+scol.
#define LOAD_CHUNK(dbase_)                                                        \
    _Pragma("unroll") for (int it = 0; it < 4; ++it)                              \
    _Pragma("unroll") for (int ci = 0; ci < 4; ++ci) {                            \
        int row = it * 16 + srow;                                                 \
        int col = ci * 16 + scol;                                                 \
        v[it * 4 + ci] = *(const float4*)(x + (size_t)(tok0 + row) * D_DIM +      \
                                          kbase + (dbase_) + col);                \
    }

    LOAD_CHUNK(0)
    __syncthreads();   // wmS ready

    for (int s = 0; s < 2; ++s) {
        const int dbase = s * 64;
        // commit current chunk to LDS (+ fused bf16 store to xb)
#pragma unroll
        for (int it = 0; it < 4; ++it)
#pragma unroll
            for (int ci = 0; ci < 4; ++ci) {
                int row = it * 16 + srow;
                int col = ci * 16 + scol;
                *(float4*)&xs[row][col] = v[it * 4 + ci];
                if (WRITE_XB) {
                    uint2 p = pack4(v[it * 4 + ci]);
                    *(uint2*)(xb + (size_t)(tok0 + row) * D_DIM + kbase + dbase + col) = p;
                }
            }
        __syncthreads();
        if (s < 1) { LOAD_CHUNK(dbase + 64) }   // prefetch; latency hidden under dfma
        // compute: lane reads its own token row; Wm reads are uniform (broadcast)
#pragma unroll
        for (int j4 = 0; j4 < 16; ++j4) {
            float4 xv = *(const float4*)&xs[lane][j4 * 4];
#pragma unroll
            for (int g = 0; g < 8; ++g) {
                float4 wv = *(const float4*)&wmS[g][dbase + j4 * 4];
                acc[g] += (double)xv.x * (double)wv.x;
                acc[g] += (double)xv.y * (double)wv.y;
                acc[g] += (double)xv.z * (double)wv.z;
                acc[g] += (double)xv.w * (double)wv.w;
            }
        }
        __syncthreads();   // xs consumed before next overwrite
    }
#undef LOAD_CHUNK

    double* dst = part + (((size_t)t * GATE_Q + q) * 64 + lane) * 8;
#pragma unroll
    for (int g = 0; g < 8; ++g) dst[g] = acc[g];
}

// Gate phase 2: one thread per token — sum 16 chunk-partials + bm, argmax
// (strict > == top_k lowest-index tie rule), bucket via atomic.
__global__ __launch_bounds__(256)
void gate_combine_kernel(const double* __restrict__ part, const float* __restrict__ bm,
                         int* __restrict__ cnt, int* __restrict__ bucket) {
    int tok = blockIdx.x * 256 + threadIdx.x;
    int t = tok >> 6, L = tok & 63;
    double s[8];
#pragma unroll
    for (int g = 0; g < 8; ++g) s[g] = (double)bm[g];
#pragma unroll
    for (int q = 0; q < GATE_Q; ++q) {
        const double* p = part + (((size_t)t * GATE_Q + q) * 64 + L) * 8;
#pragma unroll
        for (int g = 0; g < 8; ++g) s[g] += p[g];
    }
    double best = s[0]; int bg = 0;
#pragma unroll
    for (int g = 1; g < 8; ++g)
        if (s[g] > best) { best = s[g]; bg = g; }
    int pos = atomicAdd(&cnt[bg], 1);
    bucket[bg * T_TOK + pos] = tok;
}

// ---------------------------------------------------------------------------
// bf16 MFMA GEMM with row gather via bucket.
// 128(M) x 64(N) tile, BK=32, 256 threads = 4 waves, each wave a 64x32
// sub-tile via 4x2 16x16x32 MFMAs.  (Was 128x128 / 64x64-per-wave: sparsity
// caps active blocks at ~2/CU -> latency-bound at Occupancy 18%, MfmaUtil 19%.
// Halving N doubles active blocks: ~4/CU gemm1, ~8/CU gemm2.)
// A_BF16/B_BF16: operand is pre-converted bf16 (async global_load_lds staging)
// vs fp32 global (register-load + in-register RNE pack + ds_write).
// IS_G1: A rows gathered from x-like [*, KDIM]; B rows = W1[g*GF+nx0+..], out bf16 relu(.+b1)
// else : A rows gathered from Hb [*, GF]; B rows = W2[nx0+..] col-offset g*GF, out f32 .+b2
// ---------------------------------------------------------------------------
template <int KDIM, bool IS_G1, bool A_BF16, bool B_BF16>
__global__ __launch_bounds__(256)
void mfma_gemm(const void* __restrict__ Aop, const void* __restrict__ Bop,
               const float* __restrict__ bias,
               const int* __restrict__ cnt, const int* __restrict__ bucket,
               unsigned short* __restrict__ outH, float* __restrict__ outF) {
    const int g  = blockIdx.z;
    const int n  = cnt[g];
    const int t0 = blockIdx.y * 128;
    if (t0 >= n) return;
    const int nx0 = blockIdx.x * 64;
    const int tid  = threadIdx.x;
    const int lane = tid & 63;
    const int wv   = tid >> 6;

    __shared__ int toks[128];
    __shared__ __align__(16) unsigned short As[128 * 32];  // [row][k], 64B rows, 8 KiB
    __shared__ __align__(16) unsigned short Bs[64 * 32];   // 4 KiB

    if (tid < 128) {
        int r = t0 + tid;
        if (r >= n) r = n - 1;       // clamp: duplicate last valid token, masked on store
        toks[tid] = bucket[g * T_TOK + r];
    }
    __syncthreads();

    const size_t bstride = IS_G1 ? (size_t)KDIM : (size_t)F_DIM;
    const size_t brow0   = IS_G1 ? (size_t)(g * GF + nx0) : (size_t)nx0;
    const size_t bcol    = IS_G1 ? 0 : (size_t)(g * GF);

    // --- bf16 async staging mapping: chunk c, row c>>2, seg c&3 ---
    // A: 512 chunks -> 2 per thread.  B: 256 chunks -> 1 per thread.
    const int lrow = tid >> 2;
    const int lseg = tid & 3;
    const unsigned short* aP0 = nullptr; const unsigned short* aP1 = nullptr;
    const unsigned short* bP0 = nullptr;
    char *ldsA0 = nullptr, *ldsA1 = nullptr, *ldsB0 = nullptr;
    if (A_BF16) {
        const unsigned short* Ab = (const unsigned short*)Aop;
        aP0 = Ab + (size_t)toks[lrow] * KDIM + lseg * 8;
        aP1 = Ab + (size_t)toks[64 + lrow] * KDIM + lseg * 8;
        ldsA0 = (char*)As + tid * 16;
        ldsA1 = (char*)As + 4096 + tid * 16;
    }
    if (B_BF16) {
        const unsigned short* Bb = (const unsigned short*)Bop;
        bP0 = Bb + (brow0 + lrow) * bstride + bcol + lseg * 8;
        ldsB0 = (char*)Bs + tid * 16;
    }

    // --- fp32 register staging mapping ---
    // A: row tid>>1, 16 k-elems at (tid&1)*16.  B: row tid>>2, 8 k-elems at (tid&3)*8.
    const int frw = tid >> 1;
    const int fsg = (tid & 1) * 16;
    const float* aF = nullptr; const float* bF = nullptr;
    char *ldsAf = nullptr, *ldsBf = nullptr;
    if (!A_BF16) {
        aF = (const float*)Aop + (size_t)toks[frw] * KDIM + fsg;
        ldsAf = (char*)As + frw * 64 + (tid & 1) * 32;
    }
    if (!B_BF16) {
        bF = (const float*)Bop + (brow0 + (tid >> 2)) * bstride + bcol + (tid & 3) * 8;
        ldsBf = (char*)Bs + (tid >> 2) * 64 + (tid & 3) * 16;
    }

    f32x4 acc[4][2];
#pragma unroll
    for (int mi = 0; mi < 4; ++mi)
#pragma unroll
        for (int ni = 0; ni < 2; ++ni)
            acc[mi][ni] = (f32x4){0.f, 0.f, 0.f, 0.f};

    const int wr   = (wv >> 1) * 64;   // wave row offset in 128-tile
    const int wc   = (wv & 1) * 32;    // wave col offset in 64-tile
    const int frow = lane & 15;
    const int kh   = lane >> 4;

    for (int k0 = 0; k0 < KDIM; k0 += 32) {
        __syncthreads();               // prev iter's LDS reads done
        if (A_BF16) { async_load16(aP0 + k0, ldsA0); async_load16(aP1 + k0, ldsA1); }
        if (B_BF16) { async_load16(bP0 + k0, ldsB0); }
        if (!A_BF16) {
            float4 v0 = *(const float4*)(aF + k0);
            float4 v1 = *(const float4*)(aF + k0 + 4);
            float4 v2 = *(const float4*)(aF + k0 + 8);
            float4 v3 = *(const float4*)(aF + k0 + 12);
            uint2 p0 = pack4(v0), p1 = pack4(v1), p2 = pack4(v2), p3 = pack4(v3);
            uint4 w0; w0.x = p0.x; w0.y = p0.y; w0.z = p1.x; w0.w = p1.y;
            uint4 w1; w1.x = p2.x; w1.y = p2.y; w1.z = p3.x; w1.w = p3.y;
            *(uint4*)ldsAf = w0; *(uint4*)(ldsAf + 16) = w1;
        }
        if (!B_BF16) {
            float4 v0 = *(const float4*)(bF + k0);
            float4 v1 = *(const float4*)(bF + k0 + 4);
            uint2 p0 = pack4(v0), p1 = pack4(v1);
            uint4 w0; w0.x = p0.x; w0.y = p0.y; w0.z = p1.x; w0.w = p1.y;
            *(uint4*)ldsBf = w0;
        }
        __syncthreads();               // staging visible (vmcnt + lgkmcnt drained)
        bf16x8 af[4], bfr[2];
#pragma unroll
        for (int mi = 0; mi < 4; ++mi)
            af[mi] = *(const bf16x8*)((const char*)As + (size_t)(wr + mi * 16 + frow) * 64 + kh * 16);
#pragma unroll
        for (int ni = 0; ni < 2; ++ni)
            bfr[ni] = *(const bf16x8*)((const char*)Bs + (size_t)(wc + ni * 16 + frow) * 64 + kh * 16);
#pragma unroll
        for (int mi = 0; mi < 4; ++mi)
#pragma unroll
            for (int ni = 0; ni < 2; ++ni)
                acc[mi][ni] = __builtin_amdgcn_mfma_f32_16x16x32_bf16(
                    af[mi], bfr[ni], acc[mi][ni], 0, 0, 0);
    }

    // epilogue: C elem (row = mi*16 + kh*4 + v, col = ni*16 + frow)  [m89 mapping]
    const float* bptr = bias + (IS_G1 ? (g * GF + nx0) : nx0);
    float bv[2];
#pragma unroll
    for (int ni = 0; ni < 2; ++ni) bv[ni] = bptr[wc + ni * 16 + frow];

#pragma unroll
    for (int mi = 0; mi < 4; ++mi) {
#pragma unroll
        for (int v = 0; v < 4; ++v) {
            int r = wr + mi * 16 + kh * 4 + v;
            if (t0 + r < n) {
                int tok = toks[r];
                if (IS_G1) {
                    unsigned short* dst = outH + (size_t)tok * GF + nx0 + wc + frow;
#pragma unroll
                    for (int ni = 0; ni < 2; ++ni) {
                        float o = fmaxf(acc[mi][ni][v] + bv[ni], 0.f);
                        dst[ni * 16] = f2bf(o);
                    }
                } else {
                    float* dst = outF + (size_t)tok * D_DIM + nx0 + wc + frow;
#pragma unroll
                    for (int ni = 0; ni < 2; ++ni)
                        dst[ni * 16] = acc[mi][ni][v] + bv[ni];
                }
            }
        }
    }
}

extern "C" void kernel_launch(void* const* d_in, const int* in_sizes, int n_in,
                              void* d_out, int out_size, void* d_ws, size_t ws_size,
                              hipStream_t stream) {
    const float* x  = (const float*)d_in[0];
    const float* W1 = (const float*)d_in[1];
    const float* b1 = (const float*)d_in[2];
    const float* Wm = (const float*)d_in[3];
    const float* bm = (const float*)d_in[4];
    const float* W2 = (const float*)d_in[5];
    const float* b2 = (const float*)d_in[6];
    float* out = (float*)d_out;

    int* cnt    = (int*)d_ws;
    int* bucket = (int*)((char*)d_ws + 1024);
    double* part = (double*)((char*)d_ws + (1 << 19));   // 8 MiB, aliases Hb (safe: consumed first)
    unsigned short* Hb  = (unsigned short*)((char*)d_ws + (1 << 19));
    unsigned short* xb  = Hb  + (size_t)T_TOK * GF;
    unsigned short* W1b = xb  + (size_t)T_TOK * D_DIM;
    unsigned short* W2b = W1b + (size_t)F_DIM * D_DIM;

    // FAST 112.5 MiB | MID 48.5 MiB | SAFE 16.5 MiB
    const bool fast = ws_size >= 117964800ull;
    const bool mid  = ws_size >= 50855936ull;
    const int NCVT = T_TOK * D_DIM;  // == F*D == D*F == 16777216

    zero_cnt_kernel<<<1, 64, 0, stream>>>(cnt);
    if (fast || mid)
        gate_partial_kernel<true><<<dim3(GATE_Q, 128), 64, 0, stream>>>(x, Wm, xb, part);
    else
        gate_partial_kernel<false><<<dim3(GATE_Q, 128), 64, 0, stream>>>(x, Wm, nullptr, part);
    gate_combine_kernel<<<T_TOK / 256, 256, 0, stream>>>(part, bm, cnt, bucket);

    if (fast) {
        convert_kernel<<<NCVT / (256 * 8), 256, 0, stream>>>(W1, W1b, NCVT);
        convert_kernel<<<NCVT / (256 * 8), 256, 0, stream>>>(W2, W2b, NCVT);
        mfma_gemm<D_DIM, true, true, true><<<dim3(GF / 64, T_TOK / 128, G_NUM), 256, 0, stream>>>(
            xb, W1b, b1, cnt, bucket, Hb, nullptr);
        mfma_gemm<GF, false, true, true><<<dim3(D_DIM / 64, T_TOK / 128, G_NUM), 256, 0, stream>>>(
            Hb, W2b, b2, cnt, bucket, nullptr, out);
    } else if (mid) {
        mfma_gemm<D_DIM, true, true, false><<<dim3(GF / 64, T_TOK / 128, G_NUM), 256, 0, stream>>>(
            xb, W1, b1, cnt, bucket, Hb, nullptr);
        mfma_gemm<GF, false, true, false><<<dim3(D_DIM / 64, T_TOK / 128, G_NUM), 256, 0, stream>>>(
            Hb, W2, b2, cnt, bucket, nullptr, out);
    } else {
        mfma_gemm<D_DIM, true, false, false><<<dim3(GF / 64, T_TOK / 128, G_NUM), 256, 0, stream>>>(
            x, W1, b1, cnt, bucket, Hb, nullptr);
        mfma_gemm<GF, false, true, false><<<dim3(D_DIM / 64, T_TOK / 128, G_NUM), 256, 0, stream>>>(
            Hb, W2, b2, cnt, bucket, nullptr, out);
    }
}

// Round 3
// 420.063 us; speedup vs baseline: 1.0197x; 1.0197x over previous
//
#include <hip/hip_runtime.h>
#include <hip/hip_bf16.h>

// Problem constants (B=4, S=2048, D=2048, F=8192, G=8, K=1)
#define T_TOK 8192   // B*S tokens
#define D_DIM 2048
#define F_DIM 8192
#define G_NUM 8
#define GF    1024   // features per group = F/G
#define GATE_Q 16    // gate d-chunks -> 2048 one-wave blocks
#define GATE_D 128   // D_DIM / GATE_Q

typedef __attribute__((ext_vector_type(8))) short bf16x8;  // 8 bf16 (4 VGPRs)
typedef __attribute__((ext_vector_type(4))) float f32x4;

// async global->LDS, 16B per lane. HW semantics: LDS dest = wave-uniform base
// (first lane's value) + lane*16; global address is per-lane (gather is fine).
__device__ __forceinline__ void async_load16(const void* g, void* l) {
    __builtin_amdgcn_global_load_lds(
        (const __attribute__((address_space(1))) unsigned int*)g,
        (__attribute__((address_space(3))) unsigned int*)l, 16, 0, 0);
}

__device__ __forceinline__ unsigned short f2bf(float f) {
    unsigned int u = __float_as_uint(f);
    unsigned int r = (u + 0x7fffu + ((u >> 16) & 1u)) >> 16;  // RNE
    return (unsigned short)r;
}

__device__ __forceinline__ uint2 pack4(float4 v) {
    union { __hip_bfloat162 b; unsigned u; } c0, c1;
    c0.b = __float22bfloat162_rn({v.x, v.y});
    c1.b = __float22bfloat162_rn({v.z, v.w});
    uint2 r; r.x = c0.u; r.y = c1.u; return r;
}

// fp32 staging of 32 elems -> 4 swizzled 16B LDS slots (slot = (sbase+i)^rmask)
__device__ __forceinline__ void stage_f32_64(const float* src, char* rowBase,
                                             int sbase, int rmask) {
#pragma unroll
    for (int i = 0; i < 4; ++i) {
        float4 v0 = *(const float4*)(src + i * 8);
        float4 v1 = *(const float4*)(src + i * 8 + 4);
        uint2 p0 = pack4(v0), p1 = pack4(v1);
        uint4 w; w.x = p0.x; w.y = p0.y; w.z = p1.x; w.w = p1.y;
        *(uint4*)(rowBase + ((sbase + i) ^ rmask) * 16) = w;
    }
}

// ---------------------------------------------------------------------------
// ws layout:
//   [0,32B) cnt | [1KiB,257KiB) bucket[8][8192]
//   part (fp64, 8 MiB) @ 0.5 MiB -- ALIASES Hb; consumed before gemm1 writes Hb
//   Hb  @ 0.5  (16 MiB bf16 H)
//   xb  @ 16.5 (32 MiB bf16 x)          [FAST+MID]
//   W1b @ 48.5 (32 MiB), W2b @ 80.5 (32 MiB)   [FAST only]
// ---------------------------------------------------------------------------

__global__ void zero_cnt_kernel(int* __restrict__ cnt) {
    if (threadIdx.x < G_NUM) cnt[threadIdx.x] = 0;
}

// fp32 -> bf16, 8 elems/thread
__global__ __launch_bounds__(256)
void convert_kernel(const float* __restrict__ src, unsigned short* __restrict__ dst, int n) {
    int i = (blockIdx.x * 256 + threadIdx.x) * 8;
    if (i >= n) return;
    float4 a = *(const float4*)(src + i);
    float4 b = *(const float4*)(src + i + 4);
    uint2 p0 = pack4(a), p1 = pack4(b);
    uint4 o; o.x = p0.x; o.y = p0.y; o.z = p1.x; o.w = p1.y;
    *(uint4*)(dst + i) = o;
}

// ---------------------------------------------------------------------------
// Gate phase 1: lane = token. Block = 1 wave. Grid = (16 d-chunks, 128 token
// tiles) = 2048 blocks. Stage Wm chunk; stream x through LDS with register
// prefetch; 8 fp64 accs/lane. Fused fp32->bf16 x conversion (WRITE_XB).
// ---------------------------------------------------------------------------
template <bool WRITE_XB>
__global__ __launch_bounds__(64)
void gate_partial_kernel(const float* __restrict__ x, const float* __restrict__ Wm,
                         unsigned short* __restrict__ xb, double* __restrict__ part) {
    const int q     = blockIdx.x;      // d-chunk
    const int t     = blockIdx.y;      // token tile
    const int lane  = threadIdx.x;
    const int tok0  = t * 64;
    const int kbase = q * GATE_D;

    __shared__ float wmS[8][GATE_D];   // 4 KiB, wave-uniform reads (broadcast)
    __shared__ float xs[64][68];       // 17.4 KiB; stride 68 floats = 17*16B

    for (int i = lane * 4; i < 8 * GATE_D; i += 64 * 4) {
        int g = i >> 7, d = i & (GATE_D - 1);
        *(float4*)&wmS[g][d] = *(const float4*)(Wm + (size_t)g * D_DIM + kbase + d);
    }

    double acc[8] = {0, 0, 0, 0, 0, 0, 0, 0};

    const int srow = lane >> 2;        // 0..15
    const int scol = (lane & 3) * 4;   // 0,4,8,12 (floats)

    float4 v[16];
#define LOAD_CHUNK(dbase_)                                                        \
    _Pragma("unroll") for (int it = 0; it < 4; ++it)                              \
    _Pragma("unroll") for (int ci = 0; ci < 4; ++ci) {                            \
        int row = it * 16 + srow;                                                 \
        int col = ci * 16 + scol;                                                 \
        v[it * 4 + ci] = *(const float4*)(x + (size_t)(tok0 + row) * D_DIM +      \
                                          kbase + (dbase_) + col);                \
    }

    LOAD_CHUNK(0)
    __syncthreads();   // wmS ready

    for (int s = 0; s < 2; ++s) {
        const int dbase = s * 64;
#pragma unroll
        for (int it = 0; it < 4; ++it)
#pragma unroll
            for (int ci = 0; ci < 4; ++ci) {
                int row = it * 16 + srow;
                int col = ci * 16 + scol;
                *(float4*)&xs[row][col] = v[it * 4 + ci];
                if (WRITE_XB) {
                    uint2 p = pack4(v[it * 4 + ci]);
                    *(uint2*)(xb + (size_t)(tok0 + row) * D_DIM + kbase + dbase + col) = p;
                }
            }
        __syncthreads();
        if (s < 1) { LOAD_CHUNK(dbase + 64) }
#pragma unroll
        for (int j4 = 0; j4 < 16; ++j4) {
            float4 xv = *(const float4*)&xs[lane][j4 * 4];
#pragma unroll
            for (int g = 0; g < 8; ++g) {
                float4 wv = *(const float4*)&wmS[g][dbase + j4 * 4];
                acc[g] += (double)xv.x * (double)wv.x;
                acc[g] += (double)xv.y * (double)wv.y;
                acc[g] += (double)xv.z * (double)wv.z;
                acc[g] += (double)xv.w * (double)wv.w;
            }
        }
        __syncthreads();
    }
#undef LOAD_CHUNK

    double* dst = part + (((size_t)t * GATE_Q + q) * 64 + lane) * 8;
#pragma unroll
    for (int g = 0; g < 8; ++g) dst[g] = acc[g];
}

// Gate phase 2: one thread per token. 128 blocks x 64 thr.
__global__ __launch_bounds__(64)
void gate_combine_kernel(const double* __restrict__ part, const float* __restrict__ bm,
                         int* __restrict__ cnt, int* __restrict__ bucket) {
    int tok = blockIdx.x * 64 + threadIdx.x;
    int t = tok >> 6, L = tok & 63;
    double s[8];
#pragma unroll
    for (int g = 0; g < 8; ++g) s[g] = (double)bm[g];
#pragma unroll
    for (int q = 0; q < GATE_Q; ++q) {
        const double* p = part + (((size_t)t * GATE_Q + q) * 64 + L) * 8;
#pragma unroll
        for (int g = 0; g < 8; ++g) s[g] += p[g];
    }
    double best = s[0]; int bg = 0;
#pragma unroll
    for (int g = 1; g < 8; ++g)
        if (s[g] > best) { best = s[g]; bg = g; }
    int pos = atomicAdd(&cnt[bg], 1);
    bucket[bg * T_TOK + pos] = tok;
}

// ---------------------------------------------------------------------------
// bf16 MFMA GEMM with row gather via bucket.
// 128x128 tile, BK=64, 256 threads = 4 waves, each wave 64x64 via 4x4 MFMAs
// x 2 k-subslices. (Round-1 lesson: N=64 halved compute-per-barrier and
// doubled A re-fetch -> regression. Grid caps occupancy at ~2 blocks/CU, so
// the lever is compute-per-barrier: BK 32->64 halves barrier drains.)
// LDS layout: [row][slot] with slot = seg ^ (row&7) (16B slots). Staging
// pre-swizzles the GLOBAL seg (rule #21: gload_lds writes linearly); reads
// apply the same involution -> full 32-bank spread for b128 fragment reads.
// XCD remap: all nx-tiles of one t-tile -> same XCD (A-tile L2 co-location).
// ---------------------------------------------------------------------------
template <int KDIM, bool IS_G1, bool A_BF16, bool B_BF16>
__global__ __launch_bounds__(256)
void mfma_gemm(const void* __restrict__ Aop, const void* __restrict__ Bop,
               const float* __restrict__ bias,
               const int* __restrict__ cnt, const int* __restrict__ bucket,
               unsigned short* __restrict__ outH, float* __restrict__ outF) {
    const int g  = blockIdx.z;
    const int n  = cnt[g];
    constexpr int NX = IS_G1 ? (GF / 128) : (D_DIM / 128);   // 8 or 16
    // bijective XCD remap: l = a + 8b + 8*NX*c -> t = a + 8c, nx = b.
    const int l = blockIdx.y * NX + blockIdx.x;
    const int t0  = ((l & 7) + 8 * (l / (8 * NX))) * 128;
    const int nx0 = ((l >> 3) % NX) * 128;
    if (t0 >= n) return;
    const int tid  = threadIdx.x;
    const int lane = tid & 63;
    const int wv   = tid >> 6;

    __shared__ int toks[128];
    __shared__ __align__(16) unsigned short As[128 * 64];  // 16 KiB, 128B rows
    __shared__ __align__(16) unsigned short Bs[128 * 64];  // 16 KiB

    if (tid < 128) {
        int r = t0 + tid;
        if (r >= n) r = n - 1;       // clamp: duplicate last valid token, masked on store
        toks[tid] = bucket[g * T_TOK + r];
    }
    __syncthreads();

    const size_t bstride = IS_G1 ? (size_t)KDIM : (size_t)F_DIM;
    const size_t brow0   = IS_G1 ? (size_t)(g * GF + nx0) : (size_t)nx0;
    const size_t bcol    = IS_G1 ? 0 : (size_t)(g * GF);

    // --- bf16 async staging: 1024 16B-chunks per matrix, 4 per thread ---
    // chunk c = tid + 256*j: row = c>>3 = (tid>>3)+32j, lds slot = tid&7.
    // Global seg pre-swizzled: segg = (tid&7) ^ (row&7)  (row&7 const over j).
    const int arow = tid >> 3;
    const int segg = (tid & 7) ^ (arow & 7);
    const unsigned short* aP[4]; const unsigned short* bP[4];
    char* ldsA = (char*)As + tid * 16;
    char* ldsB = (char*)Bs + tid * 16;
    if (A_BF16) {
        const unsigned short* Ab = (const unsigned short*)Aop;
#pragma unroll
        for (int j = 0; j < 4; ++j)
            aP[j] = Ab + (size_t)toks[arow + 32 * j] * KDIM + segg * 8;
    }
    if (B_BF16) {
        const unsigned short* Bb = (const unsigned short*)Bop;
#pragma unroll
        for (int j = 0; j < 4; ++j)
            bP[j] = Bb + (brow0 + arow + 32 * j) * bstride + bcol + segg * 8;
    }

    // --- fp32 register staging: row = tid>>1, k-half (tid&1)*32 elems ---
    const int frw = tid >> 1;
    const int fs  = tid & 1;
    const float* aF = nullptr; const float* bF = nullptr;
    char* ldsAf = (char*)As + frw * 128;
    char* ldsBf = (char*)Bs + frw * 128;
    if (!A_BF16) aF = (const float*)Aop + (size_t)toks[frw] * KDIM + fs * 32;
    if (!B_BF16) bF = (const float*)Bop + (brow0 + frw) * bstride + bcol + fs * 32;

    f32x4 acc[4][4];
#pragma unroll
    for (int mi = 0; mi < 4; ++mi)
#pragma unroll
        for (int ni = 0; ni < 4; ++ni)
            acc[mi][ni] = (f32x4){0.f, 0.f, 0.f, 0.f};

    const int wr   = (wv >> 1) * 64;   // wave row offset
    const int wc   = (wv & 1) * 64;    // wave col offset
    const int frow = lane & 15;
    const int kh   = lane >> 4;        // 0..3
    const int xm   = frow & 7;         // read-side swizzle mask (wr,wc ≡ 0 mod 8)
    const char* aBase = (const char*)As + (size_t)(wr + frow) * 128;
    const char* bBase = (const char*)Bs + (size_t)(wc + frow) * 128;

    for (int k0 = 0; k0 < KDIM; k0 += 64) {
        __syncthreads();               // prev iter's LDS reads done
        if (A_BF16) {
#pragma unroll
            for (int j = 0; j < 4; ++j) async_load16(aP[j] + k0, ldsA + j * 4096);
        }
        if (B_BF16) {
#pragma unroll
            for (int j = 0; j < 4; ++j) async_load16(bP[j] + k0, ldsB + j * 4096);
        }
        if (!A_BF16) stage_f32_64(aF + k0, ldsAf, fs * 4, frw & 7);
        if (!B_BF16) stage_f32_64(bF + k0, ldsBf, fs * 4, frw & 7);
        __syncthreads();               // staging visible (vmcnt + lgkmcnt drained)
#pragma unroll
        for (int kk = 0; kk < 2; ++kk) {
            const int so = ((kk * 4 + kh) ^ xm) * 16;
            bf16x8 af[4], bfr[4];
#pragma unroll
            for (int mi = 0; mi < 4; ++mi)
                af[mi] = *(const bf16x8*)(aBase + mi * 2048 + so);
#pragma unroll
            for (int ni = 0; ni < 4; ++ni)
                bfr[ni] = *(const bf16x8*)(bBase + ni * 2048 + so);
#pragma unroll
            for (int mi = 0; mi < 4; ++mi)
#pragma unroll
                for (int ni = 0; ni < 4; ++ni)
                    acc[mi][ni] = __builtin_amdgcn_mfma_f32_16x16x32_bf16(
                        af[mi], bfr[ni], acc[mi][ni], 0, 0, 0);
        }
    }

    // epilogue: C elem (row = mi*16 + kh*4 + v, col = ni*16 + frow)  [m89 mapping]
    const float* bptr = bias + (IS_G1 ? (g * GF + nx0) : nx0);
    float bv[4];
#pragma unroll
    for (int ni = 0; ni < 4; ++ni) bv[ni] = bptr[wc + ni * 16 + frow];

#pragma unroll
    for (int mi = 0; mi < 4; ++mi) {
#pragma unroll
        for (int v = 0; v < 4; ++v) {
            int r = wr + mi * 16 + kh * 4 + v;
            if (t0 + r < n) {
                int tok = toks[r];
                if (IS_G1) {
                    unsigned short* dst = outH + (size_t)tok * GF + nx0 + wc + frow;
#pragma unroll
                    for (int ni = 0; ni < 4; ++ni) {
                        float o = fmaxf(acc[mi][ni][v] + bv[ni], 0.f);
                        dst[ni * 16] = f2bf(o);
                    }
                } else {
                    float* dst = outF + (size_t)tok * D_DIM + nx0 + wc + frow;
#pragma unroll
                    for (int ni = 0; ni < 4; ++ni)
                        dst[ni * 16] = acc[mi][ni][v] + bv[ni];
                }
            }
        }
    }
}

extern "C" void kernel_launch(void* const* d_in, const int* in_sizes, int n_in,
                              void* d_out, int out_size, void* d_ws, size_t ws_size,
                              hipStream_t stream) {
    const float* x  = (const float*)d_in[0];
    const float* W1 = (const float*)d_in[1];
    const float* b1 = (const float*)d_in[2];
    const float* Wm = (const float*)d_in[3];
    const float* bm = (const float*)d_in[4];
    const float* W2 = (const float*)d_in[5];
    const float* b2 = (const float*)d_in[6];
    float* out = (float*)d_out;

    int* cnt    = (int*)d_ws;
    int* bucket = (int*)((char*)d_ws + 1024);
    double* part = (double*)((char*)d_ws + (1 << 19));   // 8 MiB, aliases Hb (consumed first)
    unsigned short* Hb  = (unsigned short*)((char*)d_ws + (1 << 19));
    unsigned short* xb  = Hb  + (size_t)T_TOK * GF;
    unsigned short* W1b = xb  + (size_t)T_TOK * D_DIM;
    unsigned short* W2b = W1b + (size_t)F_DIM * D_DIM;

    // FAST 112.5 MiB | MID 48.5 MiB | SAFE 16.5 MiB
    const bool fast = ws_size >= 117964800ull;
    const bool mid  = ws_size >= 50855936ull;
    const int NCVT = T_TOK * D_DIM;  // == F*D == D*F == 16777216

    zero_cnt_kernel<<<1, 64, 0, stream>>>(cnt);
    if (fast || mid)
        gate_partial_kernel<true><<<dim3(GATE_Q, 128), 64, 0, stream>>>(x, Wm, xb, part);
    else
        gate_partial_kernel<false><<<dim3(GATE_Q, 128), 64, 0, stream>>>(x, Wm, nullptr, part);
    gate_combine_kernel<<<T_TOK / 64, 64, 0, stream>>>(part, bm, cnt, bucket);

    if (fast) {
        convert_kernel<<<NCVT / (256 * 8), 256, 0, stream>>>(W1, W1b, NCVT);
        convert_kernel<<<NCVT / (256 * 8), 256, 0, stream>>>(W2, W2b, NCVT);
        mfma_gemm<D_DIM, true, true, true><<<dim3(GF / 128, T_TOK / 128, G_NUM), 256, 0, stream>>>(
            xb, W1b, b1, cnt, bucket, Hb, nullptr);
        mfma_gemm<GF, false, true, true><<<dim3(D_DIM / 128, T_TOK / 128, G_NUM), 256, 0, stream>>>(
            Hb, W2b, b2, cnt, bucket, nullptr, out);
    } else if (mid) {
        mfma_gemm<D_DIM, true, true, false><<<dim3(GF / 128, T_TOK / 128, G_NUM), 256, 0, stream>>>(
            xb, W1, b1, cnt, bucket, Hb, nullptr);
        mfma_gemm<GF, false, true, false><<<dim3(D_DIM / 128, T_TOK / 128, G_NUM), 256, 0, stream>>>(
            Hb, W2, b2, cnt, bucket, nullptr, out);
    } else {
        mfma_gemm<D_DIM, true, false, false><<<dim3(GF / 128, T_TOK / 128, G_NUM), 256, 0, stream>>>(
            x, W1, b1, cnt, bucket, Hb, nullptr);
        mfma_gemm<GF, false, true, false><<<dim3(D_DIM / 128, T_TOK / 128, G_NUM), 256, 0, stream>>>(
            Hb, W2, b2, cnt, bucket, nullptr, out);
    }
}

// Round 4
// 419.291 us; speedup vs baseline: 1.0216x; 1.0018x over previous
//
#include <hip/hip_runtime.h>
#include <hip/hip_bf16.h>

// Problem constants (B=4, S=2048, D=2048, F=8192, G=8, K=1)
#define T_TOK 8192   // B*S tokens
#define D_DIM 2048
#define F_DIM 8192
#define G_NUM 8
#define GF    1024   // features per group = F/G
#define GATE_Q 16    // gate d-chunks -> 2048 one-wave blocks
#define GATE_D 128   // D_DIM / GATE_Q

typedef __attribute__((ext_vector_type(8))) short bf16x8;  // 8 bf16 (4 VGPRs)
typedef __attribute__((ext_vector_type(4))) float f32x4;

// async global->LDS, 16B per lane. HW semantics: LDS dest = wave-uniform base
// (first lane's value) + lane*16; global address is per-lane (gather is fine).
__device__ __forceinline__ void async_load16(const void* g, void* l) {
    __builtin_amdgcn_global_load_lds(
        (const __attribute__((address_space(1))) unsigned int*)g,
        (__attribute__((address_space(3))) unsigned int*)l, 16, 0, 0);
}

__device__ __forceinline__ unsigned short f2bf(float f) {
    unsigned int u = __float_as_uint(f);
    unsigned int r = (u + 0x7fffu + ((u >> 16) & 1u)) >> 16;  // RNE
    return (unsigned short)r;
}

__device__ __forceinline__ uint2 pack4(float4 v) {
    union { __hip_bfloat162 b; unsigned u; } c0, c1;
    c0.b = __float22bfloat162_rn({v.x, v.y});
    c1.b = __float22bfloat162_rn({v.z, v.w});
    uint2 r; r.x = c0.u; r.y = c1.u; return r;
}

// fp32 staging of 32 elems -> 4 swizzled 16B LDS slots (slot = (sbase+i)^rmask)
__device__ __forceinline__ void stage_f32_64(const float* src, char* rowBase,
                                             int sbase, int rmask) {
#pragma unroll
    for (int i = 0; i < 4; ++i) {
        float4 v0 = *(const float4*)(src + i * 8);
        float4 v1 = *(const float4*)(src + i * 8 + 4);
        uint2 p0 = pack4(v0), p1 = pack4(v1);
        uint4 w; w.x = p0.x; w.y = p0.y; w.z = p1.x; w.w = p1.y;
        *(uint4*)(rowBase + ((sbase + i) ^ rmask) * 16) = w;
    }
}

// ---------------------------------------------------------------------------
// ws layout:
//   [0,32B) cnt | [1KiB,257KiB) bucket[8][8192]
//   part (fp64, 8 MiB) @ 0.5 MiB -- ALIASES Hb; consumed before gemm1 writes Hb
//   Hb  @ 0.5  (16 MiB bf16 H)
//   xb  @ 16.5 (32 MiB bf16 x)          [FAST+MID]
//   W1b @ 48.5 (32 MiB), W2b @ 80.5 (32 MiB)   [FAST only]
// ---------------------------------------------------------------------------

__global__ void zero_cnt_kernel(int* __restrict__ cnt) {
    if (threadIdx.x < G_NUM) cnt[threadIdx.x] = 0;
}

// fp32 -> bf16, 8 elems/thread
__global__ __launch_bounds__(256)
void convert_kernel(const float* __restrict__ src, unsigned short* __restrict__ dst, int n) {
    int i = (blockIdx.x * 256 + threadIdx.x) * 8;
    if (i >= n) return;
    float4 a = *(const float4*)(src + i);
    float4 b = *(const float4*)(src + i + 4);
    uint2 p0 = pack4(a), p1 = pack4(b);
    uint4 o; o.x = p0.x; o.y = p0.y; o.z = p1.x; o.w = p1.y;
    *(uint4*)(dst + i) = o;
}

// ---------------------------------------------------------------------------
// Gate phase 1: lane = token. Block = 1 wave. Grid = (16 d-chunks, 128 token
// tiles) = 2048 blocks. Stage Wm chunk; stream x through LDS with register
// prefetch; 8 fp64 accs/lane. Fused fp32->bf16 x conversion (WRITE_XB).
// ---------------------------------------------------------------------------
template <bool WRITE_XB>
__global__ __launch_bounds__(64)
void gate_partial_kernel(const float* __restrict__ x, const float* __restrict__ Wm,
                         unsigned short* __restrict__ xb, double* __restrict__ part) {
    const int q     = blockIdx.x;      // d-chunk
    const int t     = blockIdx.y;      // token tile
    const int lane  = threadIdx.x;
    const int tok0  = t * 64;
    const int kbase = q * GATE_D;

    __shared__ float wmS[8][GATE_D];   // 4 KiB, wave-uniform reads (broadcast)
    __shared__ float xs[64][68];       // 17.4 KiB; stride 68 floats = 17*16B

    for (int i = lane * 4; i < 8 * GATE_D; i += 64 * 4) {
        int g = i >> 7, d = i & (GATE_D - 1);
        *(float4*)&wmS[g][d] = *(const float4*)(Wm + (size_t)g * D_DIM + kbase + d);
    }

    double acc[8] = {0, 0, 0, 0, 0, 0, 0, 0};

    const int srow = lane >> 2;        // 0..15
    const int scol = (lane & 3) * 4;   // 0,4,8,12 (floats)

    float4 v[16];
#define LOAD_CHUNK(dbase_)                                                        \
    _Pragma("unroll") for (int it = 0; it < 4; ++it)                              \
    _Pragma("unroll") for (int ci = 0; ci < 4; ++ci) {                            \
        int row = it * 16 + srow;                                                 \
        int col = ci * 16 + scol;                                                 \
        v[it * 4 + ci] = *(const float4*)(x + (size_t)(tok0 + row) * D_DIM +      \
                                          kbase + (dbase_) + col);                \
    }

    LOAD_CHUNK(0)
    __syncthreads();   // wmS ready

    for (int s = 0; s < 2; ++s) {
        const int dbase = s * 64;
#pragma unroll
        for (int it = 0; it < 4; ++it)
#pragma unroll
            for (int ci = 0; ci < 4; ++ci) {
                int row = it * 16 + srow;
                int col = ci * 16 + scol;
                *(float4*)&xs[row][col] = v[it * 4 + ci];
                if (WRITE_XB) {
                    uint2 p = pack4(v[it * 4 + ci]);
                    *(uint2*)(xb + (size_t)(tok0 + row) * D_DIM + kbase + dbase + col) = p;
                }
            }
        __syncthreads();
        if (s < 1) { LOAD_CHUNK(dbase + 64) }
#pragma unroll
        for (int j4 = 0; j4 < 16; ++j4) {
            float4 xv = *(const float4*)&xs[lane][j4 * 4];
#pragma unroll
            for (int g = 0; g < 8; ++g) {
                float4 wv = *(const float4*)&wmS[g][dbase + j4 * 4];
                acc[g] += (double)xv.x * (double)wv.x;
                acc[g] += (double)xv.y * (double)wv.y;
                acc[g] += (double)xv.z * (double)wv.z;
                acc[g] += (double)xv.w * (double)wv.w;
            }
        }
        __syncthreads();
    }
#undef LOAD_CHUNK

    double* dst = part + (((size_t)t * GATE_Q + q) * 64 + lane) * 8;
#pragma unroll
    for (int g = 0; g < 8; ++g) dst[g] = acc[g];
}

// Gate phase 2: one thread per token. 128 blocks x 64 thr.
__global__ __launch_bounds__(64)
void gate_combine_kernel(const double* __restrict__ part, const float* __restrict__ bm,
                         int* __restrict__ cnt, int* __restrict__ bucket) {
    int tok = blockIdx.x * 64 + threadIdx.x;
    int t = tok >> 6, L = tok & 63;
    double s[8];
#pragma unroll
    for (int g = 0; g < 8; ++g) s[g] = (double)bm[g];
#pragma unroll
    for (int q = 0; q < GATE_Q; ++q) {
        const double* p = part + (((size_t)t * GATE_Q + q) * 64 + L) * 8;
#pragma unroll
        for (int g = 0; g < 8; ++g) s[g] += p[g];
    }
    double best = s[0]; int bg = 0;
#pragma unroll
    for (int g = 1; g < 8; ++g)
        if (s[g] > best) { best = s[g]; bg = g; }
    int pos = atomicAdd(&cnt[bg], 1);
    bucket[bg * T_TOK + pos] = tok;
}

// ---------------------------------------------------------------------------
// bf16 MFMA GEMM with row gather via bucket.
// 128x128 tile, BK=64, 256 threads = 4 waves, each wave 64x64 via 4x4 MFMAs
// x 2 k-subslices.
// FAST path (A_BF16 && B_BF16): minimum-2-phase pipeline (T3 recipe):
//   double-buffered LDS; per iter {issue gload_lds for tile k+1 -> buf^1;
//   compute tile k from buf; ONE barrier (its vmcnt(0) drain comes AFTER
//   compute -> HBM latency hidden)}. Round-3 structure drained vmcnt(0)
//   BETWEEN issue and compute -> ~full VMEM latency exposed per iter
//   (~3.2k cyc/iter measured vs ~700 static floor).
// LDS: [row][slot] with slot = seg ^ (row&7) (16B slots); staging pre-swizzles
// the GLOBAL seg (rule #21), reads apply the same involution. Verified
// SQ_LDS_BANK_CONFLICT == 0 in round 3.
// Block mapping: identity (round-3 XCD remap regressed occupancy 18->12%).
// ---------------------------------------------------------------------------
template <int KDIM, bool IS_G1, bool A_BF16, bool B_BF16>
__global__ __launch_bounds__(256)
void mfma_gemm(const void* __restrict__ Aop, const void* __restrict__ Bop,
               const float* __restrict__ bias,
               const int* __restrict__ cnt, const int* __restrict__ bucket,
               unsigned short* __restrict__ outH, float* __restrict__ outF) {
    const int g  = blockIdx.z;
    const int n  = cnt[g];
    const int t0 = blockIdx.y * 128;
    if (t0 >= n) return;
    const int nx0 = blockIdx.x * 128;
    const int tid  = threadIdx.x;
    const int lane = tid & 63;
    const int wv   = tid >> 6;

    __shared__ int toks[128];
    __shared__ __align__(16) unsigned short As[2][128 * 64];  // 2 x 16 KiB
    __shared__ __align__(16) unsigned short Bs[2][128 * 64];  // 2 x 16 KiB

    if (tid < 128) {
        int r = t0 + tid;
        if (r >= n) r = n - 1;       // clamp: duplicate last valid token, masked on store
        toks[tid] = bucket[g * T_TOK + r];
    }
    __syncthreads();

    const size_t bstride = IS_G1 ? (size_t)KDIM : (size_t)F_DIM;
    const size_t brow0   = IS_G1 ? (size_t)(g * GF + nx0) : (size_t)nx0;
    const size_t bcol    = IS_G1 ? 0 : (size_t)(g * GF);

    // --- bf16 async staging: 1024 16B-chunks per matrix per tile, 4/thread ---
    // chunk c = tid + 256*j: row = c>>3 = (tid>>3)+32j, lds slot = tid&7.
    // Global seg pre-swizzled: segg = (tid&7) ^ (row&7)  (row&7 const over j).
    const int arow = tid >> 3;
    const int segg = (tid & 7) ^ (arow & 7);
    const unsigned short* aP[4]; const unsigned short* bP[4];
    char* ldsA = (char*)As + tid * 16;   // + buf*16384 + j*4096
    char* ldsB = (char*)Bs + tid * 16;
    if (A_BF16) {
        const unsigned short* Ab = (const unsigned short*)Aop;
#pragma unroll
        for (int j = 0; j < 4; ++j)
            aP[j] = Ab + (size_t)toks[arow + 32 * j] * KDIM + segg * 8;
    }
    if (B_BF16) {
        const unsigned short* Bb = (const unsigned short*)Bop;
#pragma unroll
        for (int j = 0; j < 4; ++j)
            bP[j] = Bb + (brow0 + arow + 32 * j) * bstride + bcol + segg * 8;
    }

    // --- fp32 register staging: row = tid>>1, k-half (tid&1)*32 elems ---
    const int frw = tid >> 1;
    const int fs  = tid & 1;
    const float* aF = nullptr; const float* bF = nullptr;
    char* ldsAf = (char*)As + frw * 128;
    char* ldsBf = (char*)Bs + frw * 128;
    if (!A_BF16) aF = (const float*)Aop + (size_t)toks[frw] * KDIM + fs * 32;
    if (!B_BF16) bF = (const float*)Bop + (brow0 + frw) * bstride + bcol + fs * 32;

    f32x4 acc[4][4];
#pragma unroll
    for (int mi = 0; mi < 4; ++mi)
#pragma unroll
        for (int ni = 0; ni < 4; ++ni)
            acc[mi][ni] = (f32x4){0.f, 0.f, 0.f, 0.f};

    const int wr   = (wv >> 1) * 64;   // wave row offset
    const int wc   = (wv & 1) * 64;    // wave col offset
    const int frow = lane & 15;
    const int kh   = lane >> 4;        // 0..3
    const int xm   = frow & 7;         // read-side swizzle mask (wr,wc ≡ 0 mod 8)

    // compute one 64-K LDS tile from buffer `buf`
    auto compute_tile = [&](int buf) {
        const char* aB = (const char*)As + buf * 16384 + (size_t)(wr + frow) * 128;
        const char* bB = (const char*)Bs + buf * 16384 + (size_t)(wc + frow) * 128;
        __builtin_amdgcn_s_setprio(1);
#pragma unroll
        for (int kk = 0; kk < 2; ++kk) {
            const int so = ((kk * 4 + kh) ^ xm) * 16;
            bf16x8 af[4], bfr[4];
#pragma unroll
            for (int mi = 0; mi < 4; ++mi)
                af[mi] = *(const bf16x8*)(aB + mi * 2048 + so);
#pragma unroll
            for (int ni = 0; ni < 4; ++ni)
                bfr[ni] = *(const bf16x8*)(bB + ni * 2048 + so);
#pragma unroll
            for (int mi = 0; mi < 4; ++mi)
#pragma unroll
                for (int ni = 0; ni < 4; ++ni)
                    acc[mi][ni] = __builtin_amdgcn_mfma_f32_16x16x32_bf16(
                        af[mi], bfr[ni], acc[mi][ni], 0, 0, 0);
        }
        __builtin_amdgcn_s_setprio(0);
    };

    if constexpr (A_BF16 && B_BF16) {
        // ---- minimum-2-phase pipeline: one barrier per iter, drain after compute ----
#pragma unroll
        for (int j = 0; j < 4; ++j) {          // prologue: stage tile 0 -> buf 0
            async_load16(aP[j], ldsA + j * 4096);
            async_load16(bP[j], ldsB + j * 4096);
        }
        __syncthreads();                       // vmcnt(0) drained: buf0 ready
        int cur = 0;
        for (int k0 = 0; k0 < KDIM - 64; k0 += 64) {
            const int nb = cur ^ 1;
#pragma unroll
            for (int j = 0; j < 4; ++j) {      // issue next tile (latency hides under compute)
                async_load16(aP[j] + k0 + 64, ldsA + nb * 16384 + j * 4096);
                async_load16(bP[j] + k0 + 64, ldsB + nb * 16384 + j * 4096);
            }
            compute_tile(cur);
            __syncthreads();                   // drains vmcnt(0)+lgkm AFTER compute
            cur = nb;
        }
        compute_tile(cur);                     // epilogue tile, no prefetch
    } else {
        // ---- fallback (mid/safe): two-barrier, single buffer 0 ----
        for (int k0 = 0; k0 < KDIM; k0 += 64) {
            __syncthreads();               // prev iter's LDS reads done
            if (A_BF16) {
#pragma unroll
                for (int j = 0; j < 4; ++j) async_load16(aP[j] + k0, ldsA + j * 4096);
            }
            if (B_BF16) {
#pragma unroll
                for (int j = 0; j < 4; ++j) async_load16(bP[j] + k0, ldsB + j * 4096);
            }
            if (!A_BF16) stage_f32_64(aF + k0, ldsAf, fs * 4, frw & 7);
            if (!B_BF16) stage_f32_64(bF + k0, ldsBf, fs * 4, frw & 7);
            __syncthreads();               // staging visible
            compute_tile(0);
        }
    }

    // epilogue: C elem (row = mi*16 + kh*4 + v, col = ni*16 + frow)  [m89 mapping]
    const float* bptr = bias + (IS_G1 ? (g * GF + nx0) : nx0);
    float bv[4];
#pragma unroll
    for (int ni = 0; ni < 4; ++ni) bv[ni] = bptr[wc + ni * 16 + frow];

#pragma unroll
    for (int mi = 0; mi < 4; ++mi) {
#pragma unroll
        for (int v = 0; v < 4; ++v) {
            int r = wr + mi * 16 + kh * 4 + v;
            if (t0 + r < n) {
                int tok = toks[r];
                if (IS_G1) {
                    unsigned short* dst = outH + (size_t)tok * GF + nx0 + wc + frow;
#pragma unroll
                    for (int ni = 0; ni < 4; ++ni) {
                        float o = fmaxf(acc[mi][ni][v] + bv[ni], 0.f);
                        dst[ni * 16] = f2bf(o);
                    }
                } else {
                    float* dst = outF + (size_t)tok * D_DIM + nx0 + wc + frow;
#pragma unroll
                    for (int ni = 0; ni < 4; ++ni)
                        dst[ni * 16] = acc[mi][ni][v] + bv[ni];
                }
            }
        }
    }
}

extern "C" void kernel_launch(void* const* d_in, const int* in_sizes, int n_in,
                              void* d_out, int out_size, void* d_ws, size_t ws_size,
                              hipStream_t stream) {
    const float* x  = (const float*)d_in[0];
    const float* W1 = (const float*)d_in[1];
    const float* b1 = (const float*)d_in[2];
    const float* Wm = (const float*)d_in[3];
    const float* bm = (const float*)d_in[4];
    const float* W2 = (const float*)d_in[5];
    const float* b2 = (const float*)d_in[6];
    float* out = (float*)d_out;

    int* cnt    = (int*)d_ws;
    int* bucket = (int*)((char*)d_ws + 1024);
    double* part = (double*)((char*)d_ws + (1 << 19));   // 8 MiB, aliases Hb (consumed first)
    unsigned short* Hb  = (unsigned short*)((char*)d_ws + (1 << 19));
    unsigned short* xb  = Hb  + (size_t)T_TOK * GF;
    unsigned short* W1b = xb  + (size_t)T_TOK * D_DIM;
    unsigned short* W2b = W1b + (size_t)F_DIM * D_DIM;

    // FAST 112.5 MiB | MID 48.5 MiB | SAFE 16.5 MiB
    const bool fast = ws_size >= 117964800ull;
    const bool mid  = ws_size >= 50855936ull;
    const int NCVT = T_TOK * D_DIM;  // == F*D == D*F == 16777216

    zero_cnt_kernel<<<1, 64, 0, stream>>>(cnt);
    if (fast || mid)
        gate_partial_kernel<true><<<dim3(GATE_Q, 128), 64, 0, stream>>>(x, Wm, xb, part);
    else
        gate_partial_kernel<false><<<dim3(GATE_Q, 128), 64, 0, stream>>>(x, Wm, nullptr, part);
    gate_combine_kernel<<<T_TOK / 64, 64, 0, stream>>>(part, bm, cnt, bucket);

    if (fast) {
        convert_kernel<<<NCVT / (256 * 8), 256, 0, stream>>>(W1, W1b, NCVT);
        convert_kernel<<<NCVT / (256 * 8), 256, 0, stream>>>(W2, W2b, NCVT);
        mfma_gemm<D_DIM, true, true, true><<<dim3(GF / 128, T_TOK / 128, G_NUM), 256, 0, stream>>>(
            xb, W1b, b1, cnt, bucket, Hb, nullptr);
        mfma_gemm<GF, false, true, true><<<dim3(D_DIM / 128, T_TOK / 128, G_NUM), 256, 0, stream>>>(
            Hb, W2b, b2, cnt, bucket, nullptr, out);
    } else if (mid) {
        mfma_gemm<D_DIM, true, true, false><<<dim3(GF / 128, T_TOK / 128, G_NUM), 256, 0, stream>>>(
            xb, W1, b1, cnt, bucket, Hb, nullptr);
        mfma_gemm<GF, false, true, false><<<dim3(D_DIM / 128, T_TOK / 128, G_NUM), 256, 0, stream>>>(
            Hb, W2, b2, cnt, bucket, nullptr, out);
    } else {
        mfma_gemm<D_DIM, true, false, false><<<dim3(GF / 128, T_TOK / 128, G_NUM), 256, 0, stream>>>(
            x, W1, b1, cnt, bucket, Hb, nullptr);
        mfma_gemm<GF, false, true, false><<<dim3(D_DIM / 128, T_TOK / 128, G_NUM), 256, 0, stream>>>(
            Hb, W2, b2, cnt, bucket, nullptr, out);
    }
}

// Round 7
// 402.476 us; speedup vs baseline: 1.0643x; 1.0418x over previous
//
#include <hip/hip_runtime.h>
#include <hip/hip_bf16.h>

// Problem constants (B=4, S=2048, D=2048, F=8192, G=8, K=1)
#define T_TOK 8192   // B*S tokens
#define D_DIM 2048
#define F_DIM 8192
#define G_NUM 8
#define GF    1024   // features per group = F/G
#define GATE_Q 16    // gate d-chunks -> 2048 one-wave blocks
#define GATE_D 128   // D_DIM / GATE_Q
#define MAX_TILES 72 // sum over g of ceil(cnt[g]/128) <= 64 + 8

typedef __attribute__((ext_vector_type(8))) short bf16x8;  // 8 bf16 (4 VGPRs)
typedef __attribute__((ext_vector_type(4))) float f32x4;

// async global->LDS, 16B per lane. HW semantics: LDS dest = wave-uniform base
// (first lane's value) + lane*16; global address is per-lane (gather is fine).
__device__ __forceinline__ void async_load16(const void* g, void* l) {
    __builtin_amdgcn_global_load_lds(
        (const __attribute__((address_space(1))) unsigned int*)g,
        (__attribute__((address_space(3))) unsigned int*)l, 16, 0, 0);
}

__device__ __forceinline__ unsigned short f2bf(float f) {
    unsigned int u = __float_as_uint(f);
    unsigned int r = (u + 0x7fffu + ((u >> 16) & 1u)) >> 16;  // RNE
    return (unsigned short)r;
}

__device__ __forceinline__ uint2 pack4(float4 v) {
    union { __hip_bfloat162 b; unsigned u; } c0, c1;
    c0.b = __float22bfloat162_rn({v.x, v.y});
    c1.b = __float22bfloat162_rn({v.z, v.w});
    uint2 r; r.x = c0.u; r.y = c1.u; return r;
}

// ---------------------------------------------------------------------------
// ws layout:
//   [0,32B) cnt | [64,352) tiles[72] | [1KiB,257KiB) bucket[8][8192]
//   part (fp64, 8 MiB) @ 0.5 MiB -- ALIASES Hb; consumed before gemm1 writes Hb
//   Hb  @ 0.5  (16 MiB bf16 H)
//   xb  @ 16.5 (32 MiB bf16 x)          [FAST+MID]
//   W1b @ 48.5 (32 MiB), W2b @ 80.5 (32 MiB)   [FAST only]
// ---------------------------------------------------------------------------

__global__ void zero_cnt_kernel(int* __restrict__ cnt) {
    if (threadIdx.x < G_NUM) cnt[threadIdx.x] = 0;
}

// Build compact tile list: tiles[i] = (g<<16)|tt for every 128-row t-tile of
// every group; sentinel -1 pad. Grid compaction: rounds 0-4 launched 8x-16x
// more blocks than do work (t0>=n early-return); in-order dispatch scattered
// the workers unevenly across CUs (occ 12-18% vs 25% balanced).
__global__ void tile_plan_kernel(const int* __restrict__ cnt, int* __restrict__ tiles) {
    if (threadIdx.x == 0) {
        int k = 0;
        for (int g = 0; g < G_NUM; ++g) {
            int nt = (cnt[g] + 127) >> 7;
            for (int t = 0; t < nt; ++t) tiles[k++] = (g << 16) | t;
        }
        for (int i = k; i < MAX_TILES; ++i) tiles[i] = -1;
    }
}

// fp32 -> bf16, 8 elems/thread
__global__ __launch_bounds__(256)
void convert_kernel(const float* __restrict__ src, unsigned short* __restrict__ dst, int n) {
    int i = (blockIdx.x * 256 + threadIdx.x) * 8;
    if (i >= n) return;
    float4 a = *(const float4*)(src + i);
    float4 b = *(const float4*)(src + i + 4);
    uint2 p0 = pack4(a), p1 = pack4(b);
    uint4 o; o.x = p0.x; o.y = p0.y; o.z = p1.x; o.w = p1.y;
    *(uint4*)(dst + i) = o;
}

// ---------------------------------------------------------------------------
// Gate phase 1: lane = token. Block = 1 wave. Grid = (16 d-chunks, 128 token
// tiles) = 2048 blocks. Stage Wm chunk; stream x through LDS with register
// prefetch; 8 fp64 accs/lane. Fused fp32->bf16 x conversion (WRITE_XB).
// ---------------------------------------------------------------------------
template <bool WRITE_XB>
__global__ __launch_bounds__(64)
void gate_partial_kernel(const float* __restrict__ x, const float* __restrict__ Wm,
                         unsigned short* __restrict__ xb, double* __restrict__ part) {
    const int q     = blockIdx.x;      // d-chunk
    const int t     = blockIdx.y;      // token tile
    const int lane  = threadIdx.x;
    const int tok0  = t * 64;
    const int kbase = q * GATE_D;

    __shared__ float wmS[8][GATE_D];   // 4 KiB, wave-uniform reads (broadcast)
    __shared__ float xs[64][68];       // 17.4 KiB; stride 68 floats = 17*16B

    for (int i = lane * 4; i < 8 * GATE_D; i += 64 * 4) {
        int g = i >> 7, d = i & (GATE_D - 1);
        *(float4*)&wmS[g][d] = *(const float4*)(Wm + (size_t)g * D_DIM + kbase + d);
    }

    double acc[8] = {0, 0, 0, 0, 0, 0, 0, 0};

    const int srow = lane >> 2;        // 0..15
    const int scol = (lane & 3) * 4;   // 0,4,8,12 (floats)

    float4 v[16];
#define LOAD_CHUNK(dbase_)                                                        \
    _Pragma("unroll") for (int it = 0; it < 4; ++it)                              \
    _Pragma("unroll") for (int ci = 0; ci < 4; ++ci) {                            \
        int row = it * 16 + srow;                                                 \
        int col = ci * 16 + scol;                                                 \
        v[it * 4 + ci] = *(const float4*)(x + (size_t)(tok0 + row) * D_DIM +      \
                                          kbase + (dbase_) + col);                \
    }

    LOAD_CHUNK(0)
    __syncthreads();   // wmS ready

    for (int s = 0; s < 2; ++s) {
        const int dbase = s * 64;
#pragma unroll
        for (int it = 0; it < 4; ++it)
#pragma unroll
            for (int ci = 0; ci < 4; ++ci) {
                int row = it * 16 + srow;
                int col = ci * 16 + scol;
                *(float4*)&xs[row][col] = v[it * 4 + ci];
                if (WRITE_XB) {
                    uint2 p = pack4(v[it * 4 + ci]);
                    *(uint2*)(xb + (size_t)(tok0 + row) * D_DIM + kbase + dbase + col) = p;
                }
            }
        __syncthreads();
        if (s < 1) { LOAD_CHUNK(dbase + 64) }
#pragma unroll
        for (int j4 = 0; j4 < 16; ++j4) {
            float4 xv = *(const float4*)&xs[lane][j4 * 4];
#pragma unroll
            for (int g = 0; g < 8; ++g) {
                float4 wv = *(const float4*)&wmS[g][dbase + j4 * 4];
                acc[g] += (double)xv.x * (double)wv.x;
                acc[g] += (double)xv.y * (double)wv.y;
                acc[g] += (double)xv.z * (double)wv.z;
                acc[g] += (double)xv.w * (double)wv.w;
            }
        }
        __syncthreads();
    }
#undef LOAD_CHUNK

    double* dst = part + (((size_t)t * GATE_Q + q) * 64 + lane) * 8;
#pragma unroll
    for (int g = 0; g < 8; ++g) dst[g] = acc[g];
}

// Gate phase 2: one thread per token. 128 blocks x 64 thr.
__global__ __launch_bounds__(64)
void gate_combine_kernel(const double* __restrict__ part, const float* __restrict__ bm,
                         int* __restrict__ cnt, int* __restrict__ bucket) {
    int tok = blockIdx.x * 64 + threadIdx.x;
    int t = tok >> 6, L = tok & 63;
    double s[8];
#pragma unroll
    for (int g = 0; g < 8; ++g) s[g] = (double)bm[g];
#pragma unroll
    for (int q = 0; q < GATE_Q; ++q) {
        const double* p = part + (((size_t)t * GATE_Q + q) * 64 + L) * 8;
#pragma unroll
        for (int g = 0; g < 8; ++g) s[g] += p[g];
    }
    double best = s[0]; int bg = 0;
#pragma unroll
    for (int g = 1; g < 8; ++g)
        if (s[g] > best) { best = s[g]; bg = g; }
    int pos = atomicAdd(&cnt[bg], 1);
    bucket[bg * T_TOK + pos] = tok;
}

// ---------------------------------------------------------------------------
// bf16 MFMA GEMM with row gather via bucket — round-0 inner structure (best
// measured per-dispatch: BK=32, two barriers, 16.9 KB LDS) + COMPACT GRID:
// grid = (NX, MAX_TILES); (g, t0) from tiles[]. Workers contiguous in
// dispatch order -> balanced CU packing (round-4 post-mortem: 87.5%-empty
// grids + in-order dispatch left CUs idle; occ 12-18% vs 25% balanced).
// 128x128 tile, 256 threads = 4 waves, each wave 64x64 via 4x4 MFMAs.
// ---------------------------------------------------------------------------
template <int KDIM, bool IS_G1, bool A_BF16, bool B_BF16>
__global__ __launch_bounds__(256)
void mfma_gemm(const void* __restrict__ Aop, const void* __restrict__ Bop,
               const float* __restrict__ bias,
               const int* __restrict__ cnt, const int* __restrict__ bucket,
               const int* __restrict__ tiles,
               unsigned short* __restrict__ outH, float* __restrict__ outF) {
    const int e = tiles[blockIdx.y];
    if (e < 0) return;
    const int g  = e >> 16;
    const int t0 = (e & 0xffff) * 128;
    const int n  = cnt[g];
    const int nx0 = blockIdx.x * 128;
    const int tid  = threadIdx.x;
    const int lane = tid & 63;
    const int wv   = tid >> 6;

    __shared__ int toks[128];
    __shared__ __align__(16) unsigned short As[128 * 32];  // [row][k], 64B rows
    __shared__ __align__(16) unsigned short Bs[128 * 32];

    if (tid < 128) {
        int r = t0 + tid;
        if (r >= n) r = n - 1;       // clamp: duplicate last valid token, masked on store
        toks[tid] = bucket[g * T_TOK + r];
    }
    __syncthreads();

    const size_t bstride = IS_G1 ? (size_t)KDIM : (size_t)F_DIM;
    const size_t brow0   = IS_G1 ? (size_t)(g * GF + nx0) : (size_t)nx0;
    const size_t bcol    = IS_G1 ? 0 : (size_t)(g * GF);

    // --- bf16 async staging mapping: chunk c = tid, row c>>2, seg c&3 ---
    const int lrow = tid >> 2;
    const int lseg = tid & 3;
    const unsigned short* aP0 = nullptr; const unsigned short* aP1 = nullptr;
    const unsigned short* bP0 = nullptr; const unsigned short* bP1 = nullptr;
    char *ldsA0 = nullptr, *ldsA1 = nullptr, *ldsB0 = nullptr, *ldsB1 = nullptr;
    if (A_BF16) {
        const unsigned short* Ab = (const unsigned short*)Aop;
        aP0 = Ab + (size_t)toks[lrow] * KDIM + lseg * 8;
        aP1 = Ab + (size_t)toks[64 + lrow] * KDIM + lseg * 8;
        ldsA0 = (char*)As + tid * 16;
        ldsA1 = (char*)As + 4096 + tid * 16;
    }
    if (B_BF16) {
        const unsigned short* Bb = (const unsigned short*)Bop;
        bP0 = Bb + (brow0 + lrow) * bstride + bcol + lseg * 8;
        bP1 = Bb + (brow0 + 64 + lrow) * bstride + bcol + lseg * 8;
        ldsB0 = (char*)Bs + tid * 16;
        ldsB1 = (char*)Bs + 4096 + tid * 16;
    }

    // --- fp32 register staging mapping: row tid>>1, 16 k-elems at (tid&1)*16 ---
    const int frw = tid >> 1;
    const int fsg = (tid & 1) * 16;
    const float* aF = nullptr; const float* bF = nullptr;
    char *ldsAf = nullptr, *ldsBf = nullptr;
    if (!A_BF16) {
        aF = (const float*)Aop + (size_t)toks[frw] * KDIM + fsg;
        ldsAf = (char*)As + frw * 64 + (tid & 1) * 32;
    }
    if (!B_BF16) {
        bF = (const float*)Bop + (brow0 + frw) * bstride + bcol + fsg;
        ldsBf = (char*)Bs + frw * 64 + (tid & 1) * 32;
    }

    f32x4 acc[4][4];
#pragma unroll
    for (int mi = 0; mi < 4; ++mi)
#pragma unroll
        for (int ni = 0; ni < 4; ++ni)
            acc[mi][ni] = (f32x4){0.f, 0.f, 0.f, 0.f};

    const int wr   = (wv >> 1) * 64;   // wave row offset in 128-tile
    const int wc   = (wv & 1) * 64;    // wave col offset
    const int frow = lane & 15;
    const int kh   = lane >> 4;

    for (int k0 = 0; k0 < KDIM; k0 += 32) {
        __syncthreads();               // prev iter's LDS reads done
        if (A_BF16) { async_load16(aP0 + k0, ldsA0); async_load16(aP1 + k0, ldsA1); }
        if (B_BF16) { async_load16(bP0 + k0, ldsB0); async_load16(bP1 + k0, ldsB1); }
        if (!A_BF16) {
            float4 v0 = *(const float4*)(aF + k0);
            float4 v1 = *(const float4*)(aF + k0 + 4);
            float4 v2 = *(const float4*)(aF + k0 + 8);
            float4 v3 = *(const float4*)(aF + k0 + 12);
            uint2 p0 = pack4(v0), p1 = pack4(v1), p2 = pack4(v2), p3 = pack4(v3);
            uint4 w0; w0.x = p0.x; w0.y = p0.y; w0.z = p1.x; w0.w = p1.y;
            uint4 w1; w1.x = p2.x; w1.y = p2.y; w1.z = p3.x; w1.w = p3.y;
            *(uint4*)ldsAf = w0; *(uint4*)(ldsAf + 16) = w1;
        }
        if (!B_BF16) {
            float4 v0 = *(const float4*)(bF + k0);
            float4 v1 = *(const float4*)(bF + k0 + 4);
            float4 v2 = *(const float4*)(bF + k0 + 8);
            float4 v3 = *(const float4*)(bF + k0 + 12);
            uint2 p0 = pack4(v0), p1 = pack4(v1), p2 = pack4(v2), p3 = pack4(v3);
            uint4 w0; w0.x = p0.x; w0.y = p0.y; w0.z = p1.x; w0.w = p1.y;
            uint4 w1; w1.x = p2.x; w1.y = p2.y; w1.z = p3.x; w1.w = p3.y;
            *(uint4*)ldsBf = w0; *(uint4*)(ldsBf + 16) = w1;
        }
        __syncthreads();               // staging visible (vmcnt + lgkmcnt drained)
        bf16x8 af[4], bfr[4];
#pragma unroll
        for (int mi = 0; mi < 4; ++mi)
            af[mi] = *(const bf16x8*)((const char*)As + (size_t)(wr + mi * 16 + frow) * 64 + kh * 16);
#pragma unroll
        for (int ni = 0; ni < 4; ++ni)
            bfr[ni] = *(const bf16x8*)((const char*)Bs + (size_t)(wc + ni * 16 + frow) * 64 + kh * 16);
#pragma unroll
        for (int mi = 0; mi < 4; ++mi)
#pragma unroll
            for (int ni = 0; ni < 4; ++ni)
                acc[mi][ni] = __builtin_amdgcn_mfma_f32_16x16x32_bf16(
                    af[mi], bfr[ni], acc[mi][ni], 0, 0, 0);
    }

    // epilogue: C elem (row = mi*16 + kh*4 + v, col = ni*16 + frow)  [m89 mapping]
    const float* bptr = bias + (IS_G1 ? (g * GF + nx0) : nx0);
    float bv[4];
#pragma unroll
    for (int ni = 0; ni < 4; ++ni) bv[ni] = bptr[wc + ni * 16 + frow];

#pragma unroll
    for (int mi = 0; mi < 4; ++mi) {
#pragma unroll
        for (int v = 0; v < 4; ++v) {
            int r = wr + mi * 16 + kh * 4 + v;
            if (t0 + r < n) {
                int tok = toks[r];
                if (IS_G1) {
                    unsigned short* dst = outH + (size_t)tok * GF + nx0 + wc + frow;
#pragma unroll
                    for (int ni = 0; ni < 4; ++ni) {
                        float o = fmaxf(acc[mi][ni][v] + bv[ni], 0.f);
                        dst[ni * 16] = f2bf(o);
                    }
                } else {
                    float* dst = outF + (size_t)tok * D_DIM + nx0 + wc + frow;
#pragma unroll
                    for (int ni = 0; ni < 4; ++ni)
                        dst[ni * 16] = acc[mi][ni][v] + bv[ni];
                }
            }
        }
    }
}

extern "C" void kernel_launch(void* const* d_in, const int* in_sizes, int n_in,
                              void* d_out, int out_size, void* d_ws, size_t ws_size,
                              hipStream_t stream) {
    const float* x  = (const float*)d_in[0];
    const float* W1 = (const float*)d_in[1];
    const float* b1 = (const float*)d_in[2];
    const float* Wm = (const float*)d_in[3];
    const float* bm = (const float*)d_in[4];
    const float* W2 = (const float*)d_in[5];
    const float* b2 = (const float*)d_in[6];
    float* out = (float*)d_out;

    int* cnt    = (int*)d_ws;
    int* tiles  = (int*)((char*)d_ws + 64);
    int* bucket = (int*)((char*)d_ws + 1024);
    double* part = (double*)((char*)d_ws + (1 << 19));   // 8 MiB, aliases Hb (consumed first)
    unsigned short* Hb  = (unsigned short*)((char*)d_ws + (1 << 19));
    unsigned short* xb  = Hb  + (size_t)T_TOK * GF;
    unsigned short* W1b = xb  + (size_t)T_TOK * D_DIM;
    unsigned short* W2b = W1b + (size_t)F_DIM * D_DIM;

    // FAST 112.5 MiB | MID 48.5 MiB | SAFE 16.5 MiB
    const bool fast = ws_size >= 117964800ull;
    const bool mid  = ws_size >= 50855936ull;
    const int NCVT = T_TOK * D_DIM;  // == F*D == D*F == 16777216

    zero_cnt_kernel<<<1, 64, 0, stream>>>(cnt);
    if (fast || mid)
        gate_partial_kernel<true><<<dim3(GATE_Q, 128), 64, 0, stream>>>(x, Wm, xb, part);
    else
        gate_partial_kernel<false><<<dim3(GATE_Q, 128), 64, 0, stream>>>(x, Wm, nullptr, part);
    gate_combine_kernel<<<T_TOK / 64, 64, 0, stream>>>(part, bm, cnt, bucket);
    tile_plan_kernel<<<1, 64, 0, stream>>>(cnt, tiles);

    if (fast) {
        convert_kernel<<<NCVT / (256 * 8), 256, 0, stream>>>(W1, W1b, NCVT);
        convert_kernel<<<NCVT / (256 * 8), 256, 0, stream>>>(W2, W2b, NCVT);
        mfma_gemm<D_DIM, true, true, true><<<dim3(GF / 128, MAX_TILES), 256, 0, stream>>>(
            xb, W1b, b1, cnt, bucket, tiles, Hb, nullptr);
        mfma_gemm<GF, false, true, true><<<dim3(D_DIM / 128, MAX_TILES), 256, 0, stream>>>(
            Hb, W2b, b2, cnt, bucket, tiles, nullptr, out);
    } else if (mid) {
        mfma_gemm<D_DIM, true, true, false><<<dim3(GF / 128, MAX_TILES), 256, 0, stream>>>(
            xb, W1, b1, cnt, bucket, tiles, Hb, nullptr);
        mfma_gemm<GF, false, true, false><<<dim3(D_DIM / 128, MAX_TILES), 256, 0, stream>>>(
            Hb, W2, b2, cnt, bucket, tiles, nullptr, out);
    } else {
        mfma_gemm<D_DIM, true, false, false><<<dim3(GF / 128, MAX_TILES), 256, 0, stream>>>(
            x, W1, b1, cnt, bucket, tiles, Hb, nullptr);
        mfma_gemm<GF, false, true, false><<<dim3(D_DIM / 128, MAX_TILES), 256, 0, stream>>>(
            Hb, W2, b2, cnt, bucket, tiles, nullptr, out);
    }
}